// Round 1
// baseline (159.159 us; speedup 1.0000x reference)
//
#include <hip/hip_runtime.h>
#include <math.h>

// Problem constants
#define NB 32
#define NC 64
#define NHW 3136          // 56*56
#define NM 6
#define NDIM 192
#define NHEADS 8
#define NINNER 512        // NHEADS*NC
#define NKV 3072          // NM*NINNER = per-batch flat kv size = NHEADS*NM*NC
#define CHW (NC * NHW)    // 200704

// ---------------------------------------------------------------------------
// Kernel 1: per (b, chunk): compute kflat[b][3072] = flat(z@Wk+bk)  and
//           VW[b][g][c] = sum_cc v[b][g*64+cc] * Wo[(h*64+cc)*64+c],  g=h*6+m
// grid (32, 12), block 256. Each thread computes one k element and one v
// element (idx = chunk*256+tid), v goes to LDS, then the block computes the
// 4 g-rows of VW whose inputs live exactly in this chunk (g*64 in
// [chunk*256, chunk*256+256)).
// ---------------------------------------------------------------------------
__global__ __launch_bounds__(256) void kv_proj_kernel(
    const float* __restrict__ z, const float* __restrict__ Wk,
    const float* __restrict__ bk, const float* __restrict__ Wv,
    const float* __restrict__ bv, const float* __restrict__ Wo,
    float* __restrict__ kflat, float* __restrict__ vw) {
  const int b = blockIdx.x;
  const int chunk = blockIdx.y;
  const int tid = threadIdx.x;
  const int idx = chunk * 256 + tid;   // 0..3071
  const int m = idx >> 9;              // 0..5  (uniform per wave: 64-aligned)
  const int i = idx & 511;

  __shared__ float zs[NM * NDIM];      // 1152 floats
  __shared__ float vs[256];

  for (int t = tid; t < NM * NDIM; t += 256) zs[t] = z[b * (NM * NDIM) + t];
  __syncthreads();

  float ak = bk[i];
  float av = bv[i];
  const float* zr = zs + m * NDIM;
  #pragma unroll 8
  for (int d = 0; d < NDIM; ++d) {
    const float zv = zr[d];
    ak = fmaf(zv, Wk[d * NINNER + i], ak);
    av = fmaf(zv, Wv[d * NINNER + i], av);
  }
  kflat[b * NKV + idx] = ak;
  vs[tid] = av;
  __syncthreads();

  // VW: 4 g's per chunk, 64 c's each -> exactly 256 threads.
  const int gl = tid >> 6;             // 0..3 (uniform per wave)
  const int c = tid & 63;
  const int g = chunk * 4 + gl;        // 0..47
  const int h = g / 6;
  float acc = 0.f;
  #pragma unroll 8
  for (int cc = 0; cc < NC; ++cc) {
    acc = fmaf(vs[gl * 64 + cc], Wo[(h * NC + cc) * NC + c], acc);
  }
  vw[b * NKV + g * NC + c] = acc;
}

// ---------------------------------------------------------------------------
// Kernel 2: main attention. grid (32, 49), block 64 (1 wave). One thread per
// output row n. q[64] and o[64] live in VGPRs; k/VW are wave-uniform ->
// scalar loads feeding v_fmac directly.
// out[b, n*64+c] = bo[c] + sum_{h,m} softmax_m(scale*q.k[h,m])*VW[h*6+m, c]
//                + x[b, n*64+c]
// ---------------------------------------------------------------------------
__global__ __launch_bounds__(64) void attn_kernel(
    const float* __restrict__ x, const float* __restrict__ kflat,
    const float* __restrict__ vw, const float* __restrict__ bo,
    float* __restrict__ out) {
  const int b = blockIdx.x;
  const int n = blockIdx.y * 64 + threadIdx.x;   // 0..3135, exact fit
  const float* __restrict__ xb = x + (size_t)b * CHW;

  // q[cc] = x[b, cc, n]  (coalesced across the wave: stride-1 in n)
  float q[NC];
  #pragma unroll
  for (int cc = 0; cc < NC; ++cc) q[cc] = xb[(size_t)cc * NHW + n];

  const float* __restrict__ kb = kflat + b * NKV;
  const float* __restrict__ vb = vw + b * NKV;

  float o[NC];
  #pragma unroll
  for (int c = 0; c < NC; ++c) o[c] = 0.f;

  const float scale = 0.125f;  // 64^-0.5

  #pragma unroll 1
  for (int h = 0; h < NHEADS; ++h) {
    const float* kh = kb + h * (NM * NC);
    float d[NM];
    // dots: contiguous k reads per m, 4-way split accumulators for ILP
    #pragma unroll
    for (int mm = 0; mm < NM; ++mm) {
      const float* km = kh + mm * NC;
      float a0 = 0.f, a1 = 0.f, a2 = 0.f, a3 = 0.f;
      #pragma unroll
      for (int cc = 0; cc < NC; cc += 4) {
        a0 = fmaf(q[cc + 0], km[cc + 0], a0);
        a1 = fmaf(q[cc + 1], km[cc + 1], a1);
        a2 = fmaf(q[cc + 2], km[cc + 2], a2);
        a3 = fmaf(q[cc + 3], km[cc + 3], a3);
      }
      d[mm] = (a0 + a1) + (a2 + a3);
    }
    // softmax over m (6) of scale*d
    float mx = d[0];
    #pragma unroll
    for (int mm = 1; mm < NM; ++mm) mx = fmaxf(mx, d[mm]);
    float e[NM];
    float s = 0.f;
    #pragma unroll
    for (int mm = 0; mm < NM; ++mm) {
      e[mm] = __expf((d[mm] - mx) * scale);
      s += e[mm];
    }
    const float r = 1.0f / s;
    // accumulate: o[c] += attn[m] * VW[h*6+m, c]
    const float* vh = vb + h * (NM * NC);
    #pragma unroll
    for (int mm = 0; mm < NM; ++mm) {
      const float a = e[mm] * r;
      const float* vm = vh + mm * NC;
      #pragma unroll
      for (int c = 0; c < NC; ++c) o[c] = fmaf(a, vm[c], o[c]);
    }
  }

  // epilogue: += bo + residual, float4 I/O
  const float4* __restrict__ xr = (const float4*)(xb + (size_t)n * NC);
  const float4* __restrict__ bo4 = (const float4*)bo;
  float4* __restrict__ op = (float4*)(out + (size_t)b * CHW + (size_t)n * NC);
  #pragma unroll
  for (int j = 0; j < NC / 4; ++j) {
    const float4 xv = xr[j];
    const float4 bv4 = bo4[j];
    float4 rr;
    rr.x = o[4 * j + 0] + bv4.x + xv.x;
    rr.y = o[4 * j + 1] + bv4.y + xv.y;
    rr.z = o[4 * j + 2] + bv4.z + xv.z;
    rr.w = o[4 * j + 3] + bv4.w + xv.w;
    op[j] = rr;
  }
}

extern "C" void kernel_launch(void* const* d_in, const int* in_sizes, int n_in,
                              void* d_out, int out_size, void* d_ws, size_t ws_size,
                              hipStream_t stream) {
  const float* x  = (const float*)d_in[0];
  const float* z  = (const float*)d_in[1];
  const float* Wk = (const float*)d_in[2];
  const float* bk = (const float*)d_in[3];
  const float* Wv = (const float*)d_in[4];
  const float* bv = (const float*)d_in[5];
  const float* Wo = (const float*)d_in[6];
  const float* bo = (const float*)d_in[7];
  float* out = (float*)d_out;

  float* ws = (float*)d_ws;
  float* kflat = ws;                 // NB*NKV floats
  float* vw    = ws + NB * NKV;      // NB*NKV floats  (total 786 KB)

  kv_proj_kernel<<<dim3(NB, 12), 256, 0, stream>>>(z, Wk, bk, Wv, bv, Wo,
                                                   kflat, vw);
  attn_kernel<<<dim3(NB, 49), 64, 0, stream>>>(x, kflat, vw, bo, out);
}